// Round 1
// baseline (10051.025 us; speedup 1.0000x reference)
//
#include <hip/hip_runtime.h>
#include <stdint.h>

#define B_   64
#define N_   256
#define S_   2000
#define K_   100
#define BIL_ 4
#define NITER_ 200
#define JITTER_ 1e-4f
#define SAFETY_ 0.5f

// ws layout (floats):
//   Lc   : B*N*N   col-major L per batch: Lc[b][k][i] = L[i][k]
//   Lr   : B*N*N   row-major L per batch: Lr[b][i][k] = L[i][k]
//   epsT : B*N*S   transposed eps: epsT[b][n][s] = eps[b][s][n]
#define WS_LR_OFF   ((size_t)B_ * N_ * N_)
#define WS_EPST_OFF ((size_t)2 * B_ * N_ * N_)
#define WS_FULL_FLOATS ((size_t)2 * B_ * N_ * N_ + (size_t)B_ * N_ * S_)

// ---------------- wave helpers ----------------
__device__ __forceinline__ float wred_f(float x) {
#pragma unroll
  for (int off = 32; off > 0; off >>= 1) x += __shfl_xor(x, off);
  return x;
}
__device__ __forceinline__ int wred_i(int x) {
#pragma unroll
  for (int off = 32; off > 0; off >>= 1) x += __shfl_xor(x, off);
  return x;
}

// monotone key: larger loss -> smaller key (descending radix rank)
__device__ __forceinline__ unsigned keyd(float x) {
  unsigned u = __float_as_uint(x);
  unsigned ku = (u & 0x80000000u) ? ~u : (u | 0x80000000u);
  return ~ku;
}

// Michelot exact simplex projection onto {x>=0, sum x = z}; one wave, 4 elems/lane.
// Fixed point identical to the reference's sort-based formula.
__device__ __forceinline__ float michelot4(const float vp[4], float z) {
  bool act[4] = {true, true, true, true};
  float theta = 0.0f;
  int prev = -1;
  for (int pass = 0; pass < 300; ++pass) {
    float ls = 0.0f; int lc = 0;
#pragma unroll
    for (int j = 0; j < 4; ++j) { if (act[j]) { ls += vp[j]; lc += 1; } }
    ls = wred_f(ls);
    lc = wred_i(lc);
    theta = (ls - z) / (float)lc;
    if (lc == prev) break;
    prev = lc;
#pragma unroll
    for (int j = 0; j < 4; ++j) act[j] = (vp[j] > theta);
  }
  return theta;
}

// wave0: y -> proj(y) stored to w_s; also c = mu_eff . w -> *c_sh
__device__ __forceinline__ void proj_store(const float y[4], float fl_bil, float mass, float muf,
                                           const float* __restrict__ muB, int ln,
                                           float* w_s, float* c_sh) {
  float vp[4];
#pragma unroll
  for (int j = 0; j < 4; ++j) {
    const int n = 4 * ln + j;
    vp[j] = y[j] - ((n == BIL_) ? fl_bil : 0.0f);
  }
  const float theta = michelot4(vp, mass);
  const float4 m4 = *(const float4*)(muB + 4 * ln);
  const float mm[4] = {m4.x, m4.y, m4.z, m4.w};
  float wj[4];
  float cp = 0.0f;
#pragma unroll
  for (int j = 0; j < 4; ++j) {
    const int n = 4 * ln + j;
    wj[j] = fmaxf(vp[j] - theta, 0.0f) + ((n == BIL_) ? fl_bil : 0.0f);
    cp = fmaf(muf * mm[j], wj[j], cp);
  }
  cp = wred_f(cp);
  if (ln == 0) *c_sh = cp;
  *(float4*)(w_s + 4 * ln) = make_float4(wj[0], wj[1], wj[2], wj[3]);
}

// ---------------- Cholesky: one block (256 thr) per batch ----------------
// Left-looking, 8-column panels, L kept col-major in global (Lc).
__global__ __launch_bounds__(256) void chol_kernel(const float* __restrict__ sigma,
                                                   float* __restrict__ Lc) {
  const int b = blockIdx.x;
  const int i = threadIdx.x;  // this thread owns row i
  const float* Sg = sigma + (size_t)b * N_ * N_;
  float* L = Lc + (size_t)b * N_ * N_;
  __shared__ float colbuf[8];
  __shared__ float dsh;

  for (int j0 = 0; j0 < N_; j0 += 8) {
    float s[8];
    // init from sigma (use symmetry: sigma[i][j] = sigma[j][i] -> coalesced row read)
#pragma unroll
    for (int jj = 0; jj < 8; ++jj) {
      float a = Sg[(size_t)(j0 + jj) * N_ + i];
      if (i == j0 + jj) a += JITTER_;
      s[jj] = a;
    }
    // history update: s[jj] -= sum_{k<j0} L[i][k]*L[j0+jj][k]
    for (int k = 0; k < j0; ++k) {
      const float lk = L[(size_t)k * N_ + i];
      const float4* Lk4 = (const float4*)(L + (size_t)k * N_ + j0);
      const float4 h0 = Lk4[0];
      const float4 h1 = Lk4[1];
      s[0] = fmaf(-lk, h0.x, s[0]);
      s[1] = fmaf(-lk, h0.y, s[1]);
      s[2] = fmaf(-lk, h0.z, s[2]);
      s[3] = fmaf(-lk, h0.w, s[3]);
      s[4] = fmaf(-lk, h1.x, s[4]);
      s[5] = fmaf(-lk, h1.y, s[5]);
      s[6] = fmaf(-lk, h1.z, s[6]);
      s[7] = fmaf(-lk, h1.w, s[7]);
    }
    // factor the 8-column panel
#pragma unroll
    for (int jj = 0; jj < 8; ++jj) {
      const int j = j0 + jj;
      if (i == j) dsh = sqrtf(s[jj]);
      __syncthreads();
      const float d = dsh;
      const float l = (i > j) ? (s[jj] / d) : ((i == j) ? d : 0.0f);
      if (i > j && i < j0 + 8) colbuf[i - j0] = l;
      __syncthreads();
#pragma unroll
      for (int mm = jj + 1; mm < 8; ++mm) s[mm] = fmaf(-l, colbuf[mm], s[mm]);
      L[(size_t)j * N_ + i] = l;  // zeros for i<j keep history loop branch-free
    }
    __syncthreads();
  }
}

// ---------------- Lr = transpose(Lc) per batch ----------------
__global__ __launch_bounds__(256) void ltrans_kernel(const float* __restrict__ Lc,
                                                     float* __restrict__ Lr) {
  const int b = blockIdx.x;
  const float* Lp = Lc + (size_t)b * N_ * N_;
  float* Rp = Lr + (size_t)b * N_ * N_;
  __shared__ float tl[32][33];
  const int tx = threadIdx.x & 31;
  const int ty = threadIdx.x >> 5;
  for (int kt = 0; kt < 8; ++kt) {
    for (int itt = 0; itt < 8; ++itt) {
#pragma unroll
      for (int rr = 0; rr < 4; ++rr) {
        const int k = kt * 32 + ty + 8 * rr;
        const int ii = itt * 32 + tx;
        tl[ty + 8 * rr][tx] = Lp[(size_t)k * N_ + ii];
      }
      __syncthreads();
#pragma unroll
      for (int rr = 0; rr < 4; ++rr) {
        const int ii = itt * 32 + ty + 8 * rr;
        const int k = kt * 32 + tx;
        Rp[(size_t)ii * N_ + k] = tl[tx][ty + 8 * rr];
      }
      __syncthreads();
    }
  }
}

// ---------------- epsT[b][n][s] = eps[b][s][n] ----------------
__global__ __launch_bounds__(256) void etrans_kernel(const float* __restrict__ eps,
                                                     float* __restrict__ epsT) {
  const int b = blockIdx.x;
  const int s0 = blockIdx.y * 50;
  const int t = threadIdx.x;
  __shared__ float tl[50][257];
  const float* E = eps + ((size_t)b * S_ + s0) * N_;
  for (int p = 0; p < 50; ++p) tl[p][t] = E[(size_t)p * N_ + t];
  __syncthreads();
  float* ET = epsT + (size_t)b * N_ * S_;
  const int g = t / 50, ss = t % 50;
  if (g < 5) {
    for (int q = 0; q < 52; ++q) {
      const int n = q * 5 + g;
      if (n < N_) ET[(size_t)n * S_ + s0 + ss] = tl[ss][n];
    }
  }
}

// ---------------- solver: one block (1024 thr) per batch, 200 iterations ----------------
__global__ __launch_bounds__(1024) void solve_kernel(
    const float* __restrict__ mu, const float* __restrict__ eps,
    const int* __restrict__ pcrisis, const int* __restrict__ plam,
    const float* __restrict__ Lc, const float* __restrict__ Lr,
    const float* __restrict__ epsT, float* __restrict__ out, int use_epsT) {
  const int b = blockIdx.x;
  const int t = threadIdx.x;
  const int ln = t & 63;
  const int wv = t >> 6;

  __shared__ __align__(16) float w_s[N_];
  __shared__ __align__(16) float v_s[N_];
  __shared__ __align__(16) float e_s[N_];
  __shared__ __align__(16) float u_s[N_];
  __shared__ __align__(16) float part[4][N_];
  __shared__ __align__(16) float losses[S_];
  __shared__ int lists[S_];
  __shared__ int hist[2][256];
  __shared__ float c_sh;
  __shared__ unsigned pref_sh;
  __shared__ int r_sh;
  __shared__ int lcnt;
  __shared__ float sum_sh;

  const int crisis = pcrisis[0];
  const int lamv = plam[0];
  const float muf = 1.0f + ((lamv > 0) ? (1.0f / fmaxf((float)lamv, 0.1f)) : 0.0f);
  const float fl_bil = SAFETY_ * (float)crisis;
  const float mass = 1.0f - fl_bil;

  const float* LcB = Lc + (size_t)b * N_ * N_;
  const float* LrB = Lr + (size_t)b * N_ * N_;
  const float* muB = mu + (size_t)b * N_;
  const float* epsB = eps + (size_t)b * S_ * N_;
  const float* epsTB = epsT + (size_t)b * N_ * S_;

  // ---- w0 = proj(uniform) ----
  if (t < 64) {
    float y[4];
#pragma unroll
    for (int j = 0; j < 4; ++j) y[j] = 1.0f / (float)N_;
    proj_store(y, fl_bil, mass, muf, muB, ln, w_s, &c_sh);
  }
  __syncthreads();

  // ---- v = L^T w ----
  {
    const int k = t & 255, q = t >> 8;
    const float* Lp = LrB + (size_t)(q * 64) * N_ + k;
    float acc = 0.0f;
#pragma unroll 8
    for (int ii = 0; ii < 64; ++ii) acc = fmaf(Lp[(size_t)ii * N_], w_s[q * 64 + ii], acc);
    part[q][k] = acc;
  }
  __syncthreads();
  if (t < N_) v_s[t] = part[0][t] + part[1][t] + part[2][t] + part[3][t];
  __syncthreads();

  for (int it = 0; it < NITER_; ++it) {
    // ---- stage 1: losses[s] = -(c + eps[s].v) ----
    const float cc = c_sh;
    if (use_epsT) {
      const int s1 = t;
      const int s2 = t + 1024;
      const int s2c = (s2 < S_) ? s2 : (S_ - 1);
      const float* p1 = epsTB + s1;
      const float* p2 = epsTB + s2c;
      float a0 = 0, a1 = 0, a2 = 0, a3 = 0, b0 = 0, b1 = 0, b2 = 0, b3 = 0;
#pragma unroll 4
      for (int n = 0; n < N_; n += 4) {
        const float4 vv = *(const float4*)(v_s + n);
        a0 = fmaf(p1[(size_t)(n + 0) * S_], vv.x, a0);
        b0 = fmaf(p2[(size_t)(n + 0) * S_], vv.x, b0);
        a1 = fmaf(p1[(size_t)(n + 1) * S_], vv.y, a1);
        b1 = fmaf(p2[(size_t)(n + 1) * S_], vv.y, b1);
        a2 = fmaf(p1[(size_t)(n + 2) * S_], vv.z, a2);
        b2 = fmaf(p2[(size_t)(n + 2) * S_], vv.z, b2);
        a3 = fmaf(p1[(size_t)(n + 3) * S_], vv.w, a3);
        b3 = fmaf(p2[(size_t)(n + 3) * S_], vv.w, b3);
      }
      losses[s1] = -(cc + ((a0 + a1) + (a2 + a3)));
      if (s2 < S_) losses[s2] = -(cc + ((b0 + b1) + (b2 + b3)));
    } else {
      // fallback (small ws): wave-per-scenario, shuffle reduce
      for (int s = wv; s < S_; s += 16) {
        const float4 ev = *(const float4*)(epsB + (size_t)s * N_ + 4 * ln);
        const float4 vv = *(const float4*)(v_s + 4 * ln);
        float a = ev.x * vv.x + ev.y * vv.y + ev.z * vv.z + ev.w * vv.w;
        a = wred_f(a);
        if (ln == 0) losses[s] = -(cc + a);
      }
    }
    if (t < 256) hist[0][t] = 0;
    __syncthreads();

    // ---- top-K threshold: 4-pass radix select on descending keys ----
    unsigned pref = 0;
    int r = K_;
    for (int pass = 0; pass < 4; ++pass) {
      const int shift = 24 - 8 * pass;
      int* H = hist[pass & 1];
      const unsigned msk = (pass == 0) ? 0u : (0xFFFFFFFFu << (shift + 8));
      for (int s = t; s < S_; s += 1024) {
        const unsigned kd = keyd(losses[s]);
        if ((kd & msk) == pref) atomicAdd(&H[(kd >> shift) & 255], 1);
      }
      __syncthreads();
      if (t < 64) {
        const int base = 4 * ln;
        const int c0 = H[base], c1 = H[base + 1], c2 = H[base + 2], c3 = H[base + 3];
        const int tot = c0 + c1 + c2 + c3;
        int sc = tot;
#pragma unroll
        for (int off = 1; off < 64; off <<= 1) {
          const int o = __shfl_up(sc, off);
          if (ln >= off) sc += o;
        }
        const int excl = sc - tot;
        const bool has = (excl < r) && (r <= sc);
        const unsigned long long bal = __ballot(has);
        const int lstar = __ffsll(bal) - 1;
        if (ln == lstar) {
          const int rr = r - excl;
          int d, rn;
          if (rr <= c0) { d = 0; rn = rr; }
          else if (rr <= c0 + c1) { d = 1; rn = rr - c0; }
          else if (rr <= c0 + c1 + c2) { d = 2; rn = rr - c0 - c1; }
          else { d = 3; rn = rr - c0 - c1 - c2; }
          pref_sh = pref | ((unsigned)(base + d) << shift);
          r_sh = rn;
        }
      } else if (pass < 3) {
        if (t >= 64 && t < 320) hist[(pass + 1) & 1][t - 64] = 0;
      } else {
        if (t >= 64 && t < 320) e_s[t - 64] = 0.0f;
        if (t == 320) lcnt = 0;
      }
      __syncthreads();
      pref = pref_sh;
      r = r_sh;
    }
    float thresh;
    {
      const unsigned kd = pref;
      const unsigned ub = (kd & 0x80000000u) ? kd : ((~kd) & 0x7FFFFFFFu);
      thresh = __uint_as_float(ub);
    }

    // ---- compact selected scenarios ----
    for (int s = t; s < S_; s += 1024) {
      if (losses[s] >= thresh) {
        const int p = atomicAdd(&lcnt, 1);
        lists[p] = s;
      }
    }
    __syncthreads();
    const int cnt = lcnt;
    const float weight = 1.0f / (float)((cnt > K_) ? cnt : K_);

    // ---- e = sum of selected eps rows (row-major eps, coalesced float4) ----
    {
      float ax = 0, ay = 0, az = 0, aw = 0;
      for (int p = wv; p < cnt; p += 16) {
        const float4 ev = *(const float4*)(epsB + (size_t)lists[p] * N_ + 4 * ln);
        ax += ev.x; ay += ev.y; az += ev.z; aw += ev.w;
      }
      atomicAdd(&e_s[4 * ln + 0], ax);
      atomicAdd(&e_s[4 * ln + 1], ay);
      atomicAdd(&e_s[4 * ln + 2], az);
      atomicAdd(&e_s[4 * ln + 3], aw);
    }
    __syncthreads();

    // ---- u = L e (weight folded in) ----
    {
      const int i = t & 255, q = t >> 8;
      const float* Lp = LcB + (size_t)(q * 64) * N_ + i;
      float acc = 0.0f;
#pragma unroll 8
      for (int kk = 0; kk < 64; ++kk) acc = fmaf(Lp[(size_t)kk * N_], e_s[q * 64 + kk], acc);
      part[q][i] = acc;
    }
    __syncthreads();
    if (t < N_) u_s[t] = (part[0][t] + part[1][t] + part[2][t] + part[3][t]) * weight;
    __syncthreads();

    // ---- w <- proj(w + lr*(mu_eff + u)) ----
    if (t < 64) {
      const float lr = 0.5f / sqrtf((float)it + 1.0f);
      const float4 w4 = *(const float4*)(w_s + 4 * ln);
      const float4 u4 = *(const float4*)(u_s + 4 * ln);
      const float4 m4 = *(const float4*)(muB + 4 * ln);
      float y[4];
      y[0] = w4.x + lr * (muf * m4.x + u4.x);
      y[1] = w4.y + lr * (muf * m4.y + u4.y);
      y[2] = w4.z + lr * (muf * m4.z + u4.z);
      y[3] = w4.w + lr * (muf * m4.w + u4.w);
      proj_store(y, fl_bil, mass, muf, muB, ln, w_s, &c_sh);
    }
    __syncthreads();

    // ---- v = L^T w ----
    {
      const int k = t & 255, q = t >> 8;
      const float* Lp = LrB + (size_t)(q * 64) * N_ + k;
      float acc = 0.0f;
#pragma unroll 8
      for (int ii = 0; ii < 64; ++ii) acc = fmaf(Lp[(size_t)ii * N_], w_s[q * 64 + ii], acc);
      part[q][k] = acc;
    }
    __syncthreads();
    if (t < N_) v_s[t] = part[0][t] + part[1][t] + part[2][t] + part[3][t];
    __syncthreads();
  }

  // ---- output: w / (sum + 1e-8) ----
  if (t < 64) {
    const float4 w4 = *(const float4*)(w_s + 4 * ln);
    const float ssum = wred_f(w4.x + w4.y + w4.z + w4.w);
    if (ln == 0) sum_sh = ssum;
  }
  __syncthreads();
  if (t < N_) out[(size_t)b * N_ + t] = fmaxf(w_s[t], 0.0f) / (sum_sh + 1e-8f);
}

extern "C" void kernel_launch(void* const* d_in, const int* in_sizes, int n_in,
                              void* d_out, int out_size, void* d_ws, size_t ws_size,
                              hipStream_t stream) {
  const float* mu = (const float*)d_in[0];
  const float* sigma = (const float*)d_in[1];
  const float* eps = (const float*)d_in[2];
  const int* crisis = (const int*)d_in[3];
  const int* lam = (const int*)d_in[4];
  float* out = (float*)d_out;
  float* ws = (float*)d_ws;

  float* Lc = ws;
  float* Lr = ws + WS_LR_OFF;
  float* epsT = ws + WS_EPST_OFF;
  const int use_epsT = (ws_size >= WS_FULL_FLOATS * sizeof(float)) ? 1 : 0;

  chol_kernel<<<dim3(B_), dim3(N_), 0, stream>>>(sigma, Lc);
  ltrans_kernel<<<dim3(B_), dim3(256), 0, stream>>>(Lc, Lr);
  if (use_epsT) etrans_kernel<<<dim3(B_, S_ / 50), dim3(256), 0, stream>>>(eps, epsT);
  solve_kernel<<<dim3(B_), dim3(1024), 0, stream>>>(mu, eps, crisis, lam, Lc, Lr,
                                                    use_epsT ? epsT : ws, out, use_epsT);
}

// Round 2
// 7841.035 us; speedup vs baseline: 1.2818x; 1.2818x over previous
//
#include <hip/hip_runtime.h>
#include <stdint.h>

#define B_   64
#define N_   256
#define S_   2000
#define K_   100
#define BIL_ 4
#define NITER_ 200
#define JITTER_ 1e-4f
#define SAFETY_ 0.5f
#define PART_ 4
#define SCH_  (S_ / PART_)   // 500 scenarios per block

// ---- ws layout (offsets in float units) ----
#define OFF_LC    ((size_t)0)                                  // fp32 L col-major (chol output)
#define OFF_LC16  ((size_t)B_ * N_ * N_)                       // bf16 L col-major
#define OFF_LR16  (OFF_LC16 + (size_t)B_ * N_ * N_ / 2)       // bf16 L row-major
#define OFF_EPST  (OFF_LR16 + (size_t)B_ * N_ * N_ / 2)       // bf16 epsT[b][n][s]
#define OFF_EPSRM (OFF_EPST + (size_t)B_ * N_ * S_ / 2)       // bf16 eps[b][s][n]
#define OFF_LOSS  (OFF_EPSRM + (size_t)B_ * S_ * N_ / 2)      // fp32 losses, double-buffered
#define OFF_BAR   (OFF_LOSS + (size_t)2 * B_ * S_)            // int barrier counters
// total ~25.03M floats ~100 MB (round-1 used 165 MB successfully)

// ---------------- helpers ----------------
__device__ __forceinline__ float wred_f(float x) {
#pragma unroll
  for (int off = 32; off > 0; off >>= 1) x += __shfl_xor(x, off);
  return x;
}
__device__ __forceinline__ int wred_i(int x) {
#pragma unroll
  for (int off = 32; off > 0; off >>= 1) x += __shfl_xor(x, off);
  return x;
}
__device__ __forceinline__ unsigned keyd(float x) {
  unsigned u = __float_as_uint(x);
  unsigned ku = (u & 0x80000000u) ? ~u : (u | 0x80000000u);
  return ~ku;
}
__device__ __forceinline__ uint16_t f2b(float f) {  // RNE fp32->bf16
  uint32_t u = __float_as_uint(f);
  uint32_t r = u + 0x7FFFu + ((u >> 16) & 1u);
  return (uint16_t)(r >> 16);
}
__device__ __forceinline__ float blo(uint32_t u) { return __uint_as_float(u << 16); }
__device__ __forceinline__ float bhi(uint32_t u) { return __uint_as_float(u & 0xFFFF0000u); }

// Michelot exact simplex projection (fixed point == reference sort formula); one wave.
__device__ __forceinline__ float michelot4(const float vp[4], float z) {
  bool act[4] = {true, true, true, true};
  float theta = 0.0f;
  int prev = -1;
  for (int pass = 0; pass < 300; ++pass) {
    float ls = 0.0f; int lc = 0;
#pragma unroll
    for (int j = 0; j < 4; ++j) { if (act[j]) { ls += vp[j]; lc += 1; } }
    ls = wred_f(ls);
    lc = wred_i(lc);
    theta = (ls - z) / (float)lc;
    if (lc == prev) break;
    prev = lc;
#pragma unroll
    for (int j = 0; j < 4; ++j) act[j] = (vp[j] > theta);
  }
  return theta;
}

__device__ __forceinline__ void proj_store(const float y[4], float fl_bil, float mass, float muf,
                                           const float* __restrict__ muB, int ln,
                                           float* w_s, float* c_sh) {
  float vp[4];
#pragma unroll
  for (int j = 0; j < 4; ++j) {
    const int n = 4 * ln + j;
    vp[j] = y[j] - ((n == BIL_) ? fl_bil : 0.0f);
  }
  const float theta = michelot4(vp, mass);
  const float4 m4 = *(const float4*)(muB + 4 * ln);
  const float mm[4] = {m4.x, m4.y, m4.z, m4.w};
  float wj[4];
  float cp = 0.0f;
#pragma unroll
  for (int j = 0; j < 4; ++j) {
    const int n = 4 * ln + j;
    wj[j] = fmaxf(vp[j] - theta, 0.0f) + ((n == BIL_) ? fl_bil : 0.0f);
    cp = fmaf(muf * mm[j], wj[j], cp);
  }
  cp = wred_f(cp);
  if (ln == 0) *c_sh = cp;
  *(float4*)(w_s + 4 * ln) = make_float4(wj[0], wj[1], wj[2], wj[3]);
}

// ---------------- Cholesky: one block (256 thr) per batch ----------------
__global__ __launch_bounds__(256) void chol_kernel(const float* __restrict__ sigma,
                                                   float* __restrict__ Lc) {
  const int b = blockIdx.x;
  const int i = threadIdx.x;
  const float* Sg = sigma + (size_t)b * N_ * N_;
  float* L = Lc + (size_t)b * N_ * N_;
  __shared__ float colbuf[8];
  __shared__ float dsh;

  for (int j0 = 0; j0 < N_; j0 += 8) {
    float s[8];
#pragma unroll
    for (int jj = 0; jj < 8; ++jj) {
      float a = Sg[(size_t)(j0 + jj) * N_ + i];
      if (i == j0 + jj) a += JITTER_;
      s[jj] = a;
    }
#pragma unroll 4
    for (int k = 0; k < j0; ++k) {
      const float lk = L[(size_t)k * N_ + i];
      const float4* Lk4 = (const float4*)(L + (size_t)k * N_ + j0);
      const float4 h0 = Lk4[0];
      const float4 h1 = Lk4[1];
      s[0] = fmaf(-lk, h0.x, s[0]);
      s[1] = fmaf(-lk, h0.y, s[1]);
      s[2] = fmaf(-lk, h0.z, s[2]);
      s[3] = fmaf(-lk, h0.w, s[3]);
      s[4] = fmaf(-lk, h1.x, s[4]);
      s[5] = fmaf(-lk, h1.y, s[5]);
      s[6] = fmaf(-lk, h1.z, s[6]);
      s[7] = fmaf(-lk, h1.w, s[7]);
    }
#pragma unroll
    for (int jj = 0; jj < 8; ++jj) {
      const int j = j0 + jj;
      if (i == j) dsh = sqrtf(s[jj]);
      __syncthreads();
      const float d = dsh;
      const float l = (i > j) ? (s[jj] / d) : ((i == j) ? d : 0.0f);
      if (i > j && i < j0 + 8) colbuf[i - j0] = l;
      __syncthreads();
#pragma unroll
      for (int mm = jj + 1; mm < 8; ++mm) s[mm] = fmaf(-l, colbuf[mm], s[mm]);
      L[(size_t)j * N_ + i] = l;
    }
    __syncthreads();
  }
}

// ---------------- pack L: Lc fp32 -> Lc16 (bf16) + Lr16 (bf16 transposed) ----------------
__global__ __launch_bounds__(256) void lpack_kernel(const float* __restrict__ Lc,
                                                    uint16_t* __restrict__ Lc16,
                                                    uint16_t* __restrict__ Lr16) {
  const int b = blockIdx.x;
  const float* Lp = Lc + (size_t)b * N_ * N_;
  uint16_t* C16 = Lc16 + (size_t)b * N_ * N_;
  uint16_t* R16 = Lr16 + (size_t)b * N_ * N_;
  __shared__ float tl[32][33];
  const int tx = threadIdx.x & 31;
  const int ty = threadIdx.x >> 5;
  for (int kt = 0; kt < 8; ++kt) {
    for (int it = 0; it < 8; ++it) {
#pragma unroll
      for (int rr = 0; rr < 4; ++rr) {
        const int k = kt * 32 + ty + 8 * rr;
        const int ii = it * 32 + tx;
        const float v = Lp[(size_t)k * N_ + ii];
        tl[ty + 8 * rr][tx] = v;
        C16[(size_t)k * N_ + ii] = f2b(v);
      }
      __syncthreads();
#pragma unroll
      for (int rr = 0; rr < 4; ++rr) {
        const int ii = it * 32 + ty + 8 * rr;
        const int k = kt * 32 + tx;
        R16[(size_t)ii * N_ + k] = f2b(tl[tx][ty + 8 * rr]);
      }
      __syncthreads();
    }
  }
}

// ---------------- eps fp32 -> epsT16 (bf16 [b][n][s]) + epsrm16 (bf16 [b][s][n]); zero bar ----
__global__ __launch_bounds__(256) void etrans_kernel(const float* __restrict__ eps,
                                                     uint16_t* __restrict__ epsT16,
                                                     uint16_t* __restrict__ epsrm16,
                                                     int* __restrict__ bar) {
  const int b = blockIdx.x;
  const int s0 = blockIdx.y * 50;
  const int t = threadIdx.x;
  if (blockIdx.x == 0 && blockIdx.y == 0 && t < 128) bar[t] = 0;
  __shared__ float tl[50][257];
  const float* E = eps + ((size_t)b * S_ + s0) * N_;
  for (int p = 0; p < 50; ++p) tl[p][t] = E[(size_t)p * N_ + t];
  __syncthreads();
  uint16_t* RM = epsrm16 + ((size_t)b * S_ + s0) * N_;
  for (int p = 0; p < 50; ++p) RM[(size_t)p * N_ + t] = f2b(tl[p][t]);
  uint16_t* ET = epsT16 + (size_t)b * N_ * S_;
  const int g = t / 50, ss = t % 50;
  if (g < 5) {
    for (int q = 0; q < 52; ++q) {
      const int n = q * 5 + g;
      if (n < N_) ET[(size_t)n * S_ + s0 + ss] = f2b(tl[ss][n]);
    }
  }
}

// ---------------- cooperative solver: 4 blocks (1024 thr) per batch ----------------
__global__ __launch_bounds__(1024) void solve_kernel(
    const float* __restrict__ mu, const int* __restrict__ pcrisis,
    const int* __restrict__ plam, const uint16_t* __restrict__ Lc16,
    const uint16_t* __restrict__ Lr16, const uint16_t* __restrict__ epsT16,
    const uint16_t* __restrict__ epsrm16, float* __restrict__ losses_g,
    int* __restrict__ bar, float* __restrict__ out) {
  const int bx = blockIdx.x;
  const int b = bx & (B_ - 1);
  const int part = bx >> 6;     // blocks {b, b+64, b+128, b+192}: same XCD under %8 round-robin
  const int t = threadIdx.x;
  const int ln = t & 63;
  const int wv = t >> 6;
  const int s0 = part * SCH_;

  __shared__ __align__(16) float w_s[N_];
  __shared__ __align__(16) float v_s[N_];
  __shared__ __align__(16) float e_s[N_];
  __shared__ __align__(16) float u_s[N_];
  __shared__ __align__(16) float ph[PART_][SCH_];
  __shared__ __align__(16) float scratch[8][N_];
  __shared__ __align__(16) float loss_s[S_];
  __shared__ int lists[S_];
  __shared__ int hist[2][256];
  __shared__ float c_sh;
  __shared__ unsigned pref_sh;
  __shared__ int r_sh;
  __shared__ int lcnt;
  __shared__ float sum_sh;

  const int crisis = pcrisis[0];
  const int lamv = plam[0];
  const float muf = 1.0f + ((lamv > 0) ? (1.0f / fmaxf((float)lamv, 0.1f)) : 0.0f);
  const float fl_bil = SAFETY_ * (float)crisis;
  const float mass = 1.0f - fl_bil;

  const uint16_t* LcB = Lc16 + (size_t)b * N_ * N_;
  const uint16_t* LrB = Lr16 + (size_t)b * N_ * N_;
  const float* muB = mu + (size_t)b * N_;
  const uint16_t* epsTB = epsT16 + (size_t)b * N_ * S_;
  const uint16_t* epsRB = epsrm16 + (size_t)b * S_ * N_;

  // ---- w0 = proj(uniform) ----
  if (t < 64) {
    float y[4];
#pragma unroll
    for (int j = 0; j < 4; ++j) y[j] = 1.0f / (float)N_;
    proj_store(y, fl_bil, mass, muf, muB, ln, w_s, &c_sh);
  }
  __syncthreads();

  for (int it = 0; it < NITER_; ++it) {
    // ---- v = L^T w : v_k = sum_i Lr[i*N+k] * w[i]  (8 i-octants x 128 k-pairs) ----
    {
      const int oct = t >> 7, kp = t & 127;
      const uint32_t* Lp = (const uint32_t*)(LrB) + kp;
      const int i0 = 32 * oct;
      float a0 = 0.0f, a1 = 0.0f;
#pragma unroll 8
      for (int ii = 0; ii < 32; ++ii) {
        const uint32_t u = Lp[(size_t)(i0 + ii) * (N_ / 2)];
        const float ww = w_s[i0 + ii];
        a0 = fmaf(blo(u), ww, a0);
        a1 = fmaf(bhi(u), ww, a1);
      }
      *(float2*)&scratch[oct][2 * kp] = make_float2(a0, a1);
    }
    __syncthreads();
    if (t < N_) {
      v_s[t] = ((scratch[0][t] + scratch[1][t]) + (scratch[2][t] + scratch[3][t])) +
               ((scratch[4][t] + scratch[5][t]) + (scratch[6][t] + scratch[7][t]));
    }
    __syncthreads();

    // ---- stage 1: losses[s] = -(c + eps[s].v) for my 500 scenarios (pairs via uint) ----
    const float cc = c_sh;
    {
      const int q = t >> 8;        // n-quarter
      const int idx = t & 255;     // scenario-pair
      if (idx < SCH_ / 2) {
        const uint32_t* col = (const uint32_t*)(epsTB + (size_t)(64 * q) * S_ + (s0 + 2 * idx));
        float a0 = 0.0f, a1 = 0.0f;
#pragma unroll 8
        for (int j = 0; j < 64; ++j) {
          const uint32_t u = col[(size_t)j * (S_ / 2)];
          const float vv = v_s[64 * q + j];
          a0 = fmaf(blo(u), vv, a0);
          a1 = fmaf(bhi(u), vv, a1);
        }
        *(float2*)&ph[q][2 * idx] = make_float2(a0, a1);
      }
    }
    __syncthreads();
    float* lgbuf = losses_g + ((it & 1) ? (size_t)B_ * S_ : 0) + (size_t)b * S_;
    if (t < SCH_) {
      lgbuf[s0 + t] = -(cc + ((ph[0][t] + ph[1][t]) + (ph[2][t] + ph[3][t])));
    }
    __syncthreads();

    // ---- per-batch barrier (one per iteration; losses double-buffered) ----
    if (t == 0) {
      __threadfence();
      __hip_atomic_fetch_add(&bar[b], 1, __ATOMIC_RELEASE, __HIP_MEMORY_SCOPE_AGENT);
      const int target = PART_ * (it + 1);
      while (__hip_atomic_load(&bar[b], __ATOMIC_ACQUIRE, __HIP_MEMORY_SCOPE_AGENT) < target) {
        __builtin_amdgcn_s_sleep(1);
      }
    }
    __syncthreads();

    // ---- gather all 2000 losses ----
    loss_s[t] = lgbuf[t];
    if (t + 1024 < S_) loss_s[t + 1024] = lgbuf[t + 1024];
    if (t < 256) hist[0][t] = 0;
    __syncthreads();

    // ---- top-K threshold: 4-pass radix select on descending keys ----
    unsigned pref = 0;
    int r = K_;
    for (int pass = 0; pass < 4; ++pass) {
      const int shift = 24 - 8 * pass;
      int* H = hist[pass & 1];
      const unsigned msk = (pass == 0) ? 0u : (0xFFFFFFFFu << (shift + 8));
      for (int s = t; s < S_; s += 1024) {
        const unsigned kd = keyd(loss_s[s]);
        if ((kd & msk) == pref) atomicAdd(&H[(kd >> shift) & 255], 1);
      }
      __syncthreads();
      if (t < 64) {
        const int base = 4 * ln;
        const int c0 = H[base], c1 = H[base + 1], c2 = H[base + 2], c3 = H[base + 3];
        const int tot = c0 + c1 + c2 + c3;
        int sc = tot;
#pragma unroll
        for (int off = 1; off < 64; off <<= 1) {
          const int o = __shfl_up(sc, off);
          if (ln >= off) sc += o;
        }
        const int excl = sc - tot;
        const bool has = (excl < r) && (r <= sc);
        const unsigned long long bal = __ballot(has);
        const int lstar = __ffsll(bal) - 1;
        if (ln == lstar) {
          const int rr = r - excl;
          int d, rn;
          if (rr <= c0) { d = 0; rn = rr; }
          else if (rr <= c0 + c1) { d = 1; rn = rr - c0; }
          else if (rr <= c0 + c1 + c2) { d = 2; rn = rr - c0 - c1; }
          else { d = 3; rn = rr - c0 - c1 - c2; }
          pref_sh = pref | ((unsigned)(base + d) << shift);
          r_sh = rn;
        }
      } else if (pass < 3) {
        if (t >= 64 && t < 320) hist[(pass + 1) & 1][t - 64] = 0;
      } else {
        if (t >= 64 && t < 320) e_s[t - 64] = 0.0f;
        if (t == 320) lcnt = 0;
      }
      __syncthreads();
      pref = pref_sh;
      r = r_sh;
    }
    float thresh;
    {
      const unsigned kd = pref;
      const unsigned ub = (kd & 0x80000000u) ? kd : ((~kd) & 0x7FFFFFFFu);
      thresh = __uint_as_float(ub);
    }

    // ---- compact selected scenarios ----
    for (int s = t; s < S_; s += 1024) {
      if (loss_s[s] >= thresh) {
        const int p = atomicAdd(&lcnt, 1);
        lists[p] = s;
      }
    }
    __syncthreads();
    const int cnt = lcnt;
    const float weight = 1.0f / (float)((cnt > K_) ? cnt : K_);

    // ---- e = sum of selected eps rows (bf16 row-major, uint2 per lane) ----
    {
      float ax = 0, ay = 0, az = 0, aw = 0;
      for (int p = wv; p < cnt; p += 16) {
        const uint2 uu = *(const uint2*)((const uint32_t*)(epsRB + (size_t)lists[p] * N_) + 2 * ln);
        ax += blo(uu.x); ay += bhi(uu.x); az += blo(uu.y); aw += bhi(uu.y);
      }
      atomicAdd(&e_s[4 * ln + 0], ax);
      atomicAdd(&e_s[4 * ln + 1], ay);
      atomicAdd(&e_s[4 * ln + 2], az);
      atomicAdd(&e_s[4 * ln + 3], aw);
    }
    __syncthreads();

    // ---- u = L e : u_i = sum_k Lc[k*N+i] e[k]  (8 k-octants x 128 i-pairs) ----
    {
      const int oct = t >> 7, ip = t & 127;
      const uint32_t* Lp = (const uint32_t*)(LcB) + ip;
      const int k0 = 32 * oct;
      float a0 = 0.0f, a1 = 0.0f;
#pragma unroll 8
      for (int kk = 0; kk < 32; ++kk) {
        const uint32_t u = Lp[(size_t)(k0 + kk) * (N_ / 2)];
        const float ee = e_s[k0 + kk];
        a0 = fmaf(blo(u), ee, a0);
        a1 = fmaf(bhi(u), ee, a1);
      }
      *(float2*)&scratch[oct][2 * ip] = make_float2(a0, a1);
    }
    __syncthreads();
    if (t < N_) {
      u_s[t] = (((scratch[0][t] + scratch[1][t]) + (scratch[2][t] + scratch[3][t])) +
                ((scratch[4][t] + scratch[5][t]) + (scratch[6][t] + scratch[7][t]))) * weight;
    }
    __syncthreads();

    // ---- w <- proj(w + lr*(mu_eff + u)) ----
    if (t < 64) {
      const float lr = 0.5f / sqrtf((float)it + 1.0f);
      const float4 w4 = *(const float4*)(w_s + 4 * ln);
      const float4 u4 = *(const float4*)(u_s + 4 * ln);
      const float4 m4 = *(const float4*)(muB + 4 * ln);
      float y[4];
      y[0] = w4.x + lr * (muf * m4.x + u4.x);
      y[1] = w4.y + lr * (muf * m4.y + u4.y);
      y[2] = w4.z + lr * (muf * m4.z + u4.z);
      y[3] = w4.w + lr * (muf * m4.w + u4.w);
      proj_store(y, fl_bil, mass, muf, muB, ln, w_s, &c_sh);
    }
    __syncthreads();
  }

  // ---- output (part 0 only): w / (sum + 1e-8) ----
  if (part == 0) {
    if (t < 64) {
      const float4 w4 = *(const float4*)(w_s + 4 * ln);
      const float ssum = wred_f(w4.x + w4.y + w4.z + w4.w);
      if (ln == 0) sum_sh = ssum;
    }
    __syncthreads();
    if (t < N_) out[(size_t)b * N_ + t] = fmaxf(w_s[t], 0.0f) / (sum_sh + 1e-8f);
  }
}

extern "C" void kernel_launch(void* const* d_in, const int* in_sizes, int n_in,
                              void* d_out, int out_size, void* d_ws, size_t ws_size,
                              hipStream_t stream) {
  const float* mu = (const float*)d_in[0];
  const float* sigma = (const float*)d_in[1];
  const float* eps = (const float*)d_in[2];
  const int* crisis = (const int*)d_in[3];
  const int* lam = (const int*)d_in[4];
  float* out = (float*)d_out;
  float* ws = (float*)d_ws;

  float* Lc = ws + OFF_LC;
  uint16_t* Lc16 = (uint16_t*)(ws + OFF_LC16);
  uint16_t* Lr16 = (uint16_t*)(ws + OFF_LR16);
  uint16_t* epsT16 = (uint16_t*)(ws + OFF_EPST);
  uint16_t* epsrm16 = (uint16_t*)(ws + OFF_EPSRM);
  float* losses_g = ws + OFF_LOSS;
  int* bar = (int*)(ws + OFF_BAR);

  chol_kernel<<<dim3(B_), dim3(N_), 0, stream>>>(sigma, Lc);
  lpack_kernel<<<dim3(B_), dim3(256), 0, stream>>>(Lc, Lc16, Lr16);
  etrans_kernel<<<dim3(B_, S_ / 50), dim3(256), 0, stream>>>(eps, epsT16, epsrm16, bar);

  void* args[] = {(void*)&mu,      (void*)&crisis,  (void*)&lam,    (void*)&Lc16,
                  (void*)&Lr16,    (void*)&epsT16,  (void*)&epsrm16, (void*)&losses_g,
                  (void*)&bar,     (void*)&out};
  hipLaunchCooperativeKernel((void*)solve_kernel, dim3(PART_ * B_), dim3(1024), args, 0, stream);
}

// Round 3
// 4883.347 us; speedup vs baseline: 2.0582x; 1.6057x over previous
//
#include <hip/hip_runtime.h>
#include <stdint.h>

#define B_   64
#define N_   256
#define S_   2000
#define K_   100
#define BIL_ 4
#define NITER_ 200
#define JITTER_ 1e-4f
#define SAFETY_ 0.5f
#define PART_ 4
#define SCH_  (S_ / PART_)   // 500 scenarios per block

// ---- ws layout (offsets in float units) ----
// fp32 Lc (chol output) aliases the epsrm16 region: chol -> lpack read it before
// etrans overwrites (kernels serialize on the stream).
#define OFF_LC16  ((size_t)0)                                   // bf16 L col-major
#define OFF_LR16  (OFF_LC16 + (size_t)B_ * N_ * N_ / 2)         // bf16 L row-major
#define OFF_EPST  (OFF_LR16 + (size_t)B_ * N_ * N_ / 2)         // bf16 epsT[b][n][s]
#define OFF_EPSRM (OFF_EPST + (size_t)B_ * N_ * S_ / 2)         // bf16 eps[b][s][n] (& temp fp32 Lc)
#define OFF_LOSS  (OFF_EPSRM + (size_t)B_ * S_ * N_ / 2)        // uint loss bits, double-buffered
#define OFF_BAR   (OFF_LOSS + (size_t)2 * B_ * S_)              // int barrier counters
// total ~148.9 MB (< round-1's proven 164.6 MB)

// ---------------- helpers ----------------
__device__ __forceinline__ float wred_f(float x) {
#pragma unroll
  for (int off = 32; off > 0; off >>= 1) x += __shfl_xor(x, off);
  return x;
}
__device__ __forceinline__ int wred_i(int x) {
#pragma unroll
  for (int off = 32; off > 0; off >>= 1) x += __shfl_xor(x, off);
  return x;
}
__device__ __forceinline__ unsigned keyd(float x) {
  unsigned u = __float_as_uint(x);
  unsigned ku = (u & 0x80000000u) ? ~u : (u | 0x80000000u);
  return ~ku;
}
__device__ __forceinline__ uint16_t f2b(float f) {  // RNE fp32->bf16
  uint32_t u = __float_as_uint(f);
  uint32_t r = u + 0x7FFFu + ((u >> 16) & 1u);
  return (uint16_t)(r >> 16);
}
__device__ __forceinline__ float blo(uint32_t u) { return __uint_as_float(u << 16); }
__device__ __forceinline__ float bhi(uint32_t u) { return __uint_as_float(u & 0xFFFF0000u); }

// Michelot exact simplex projection (fixed point == reference sort formula); one wave.
__device__ __forceinline__ float michelot4(const float vp[4], float z) {
  bool act[4] = {true, true, true, true};
  float theta = 0.0f;
  int prev = -1;
  for (int pass = 0; pass < 300; ++pass) {
    float ls = 0.0f; int lc = 0;
#pragma unroll
    for (int j = 0; j < 4; ++j) { if (act[j]) { ls += vp[j]; lc += 1; } }
    ls = wred_f(ls);
    lc = wred_i(lc);
    theta = (ls - z) / (float)lc;
    if (lc == prev) break;
    prev = lc;
#pragma unroll
    for (int j = 0; j < 4; ++j) act[j] = (vp[j] > theta);
  }
  return theta;
}

__device__ __forceinline__ void proj_store(const float y[4], float fl_bil, float mass, float muf,
                                           const float* __restrict__ muB, int ln,
                                           float* w_s, float* c_sh) {
  float vp[4];
#pragma unroll
  for (int j = 0; j < 4; ++j) {
    const int n = 4 * ln + j;
    vp[j] = y[j] - ((n == BIL_) ? fl_bil : 0.0f);
  }
  const float theta = michelot4(vp, mass);
  const float4 m4 = *(const float4*)(muB + 4 * ln);
  const float mm[4] = {m4.x, m4.y, m4.z, m4.w};
  float wj[4];
  float cp = 0.0f;
#pragma unroll
  for (int j = 0; j < 4; ++j) {
    const int n = 4 * ln + j;
    wj[j] = fmaxf(vp[j] - theta, 0.0f) + ((n == BIL_) ? fl_bil : 0.0f);
    cp = fmaf(muf * mm[j], wj[j], cp);
  }
  cp = wred_f(cp);
  if (ln == 0) *c_sh = cp;
  *(float4*)(w_s + 4 * ln) = make_float4(wj[0], wj[1], wj[2], wj[3]);
}

// ---------------- Cholesky v3: one block (512 thr) per batch ----------------
// Left-looking, 8-col panels; history k-range split across two thread-halves;
// previous-column slab staged in LDS; 8x8 diagonal block factored by owner
// wave via shuffles (4 block-syncs per panel instead of 16+).
__global__ __launch_bounds__(512) void chol_kernel(const float* __restrict__ sigma,
                                                   float* __restrict__ Lc) {
  const int b = blockIdx.x;
  const int tid = threadIdx.x;
  const int i = tid & 255;   // row owned
  const int half = tid >> 8; // 0/1 k-range split
  const float* Sg = sigma + (size_t)b * N_ * N_;
  float* L = Lc + (size_t)b * N_ * N_;
  __shared__ __align__(16) float slab[248 * 8];   // slab[k*8+jj] = L[k][j0+jj]
  __shared__ __align__(16) float spart[256][8];   // upper-half partial sums
  __shared__ __align__(16) float pnl[64];         // panel 8x8: [r*8+m]=L val (m<r), diag=1/d

  for (int j0 = 0; j0 < N_; j0 += 8) {
    // fill slab (reads prior-panel L; loop-end sync guarantees visibility)
    for (int x = tid; x < j0 * 8; x += 512) {
      const int k = x >> 3, jj = x & 7;
      slab[x] = L[(size_t)k * N_ + (j0 + jj)];
    }
    float s[8];
    if (half == 0) {
#pragma unroll
      for (int jj = 0; jj < 8; ++jj) {
        float a = Sg[(size_t)(j0 + jj) * N_ + i];  // sigma symmetric -> coalesced
        if (i == j0 + jj) a += JITTER_;
        s[jj] = a;
      }
    } else {
#pragma unroll
      for (int jj = 0; jj < 8; ++jj) s[jj] = 0.0f;
    }
    __syncthreads();  // A: slab ready

    // history: s[jj] -= sum_k L[i][k] * L[j0+jj][k], k split across halves
    const int kb = half ? (j0 >> 1) : 0;
    const int ke = half ? j0 : (j0 >> 1);
#pragma unroll 4
    for (int k = kb; k < ke; ++k) {
      const float lk = L[(size_t)k * N_ + i];
      const float4 h0 = *(const float4*)&slab[k * 8];
      const float4 h1 = *(const float4*)&slab[k * 8 + 4];
      s[0] = fmaf(-lk, h0.x, s[0]);
      s[1] = fmaf(-lk, h0.y, s[1]);
      s[2] = fmaf(-lk, h0.z, s[2]);
      s[3] = fmaf(-lk, h0.w, s[3]);
      s[4] = fmaf(-lk, h1.x, s[4]);
      s[5] = fmaf(-lk, h1.y, s[5]);
      s[6] = fmaf(-lk, h1.z, s[6]);
      s[7] = fmaf(-lk, h1.w, s[7]);
    }
    if (half == 1) {
      *(float4*)&spart[i][0] = make_float4(s[0], s[1], s[2], s[3]);
      *(float4*)&spart[i][4] = make_float4(s[4], s[5], s[6], s[7]);
    }
    __syncthreads();  // B: partials ready

    if (half == 0) {
      const float4 p0 = *(const float4*)&spart[i][0];
      const float4 p1 = *(const float4*)&spart[i][4];
      s[0] += p0.x; s[1] += p0.y; s[2] += p0.z; s[3] += p0.w;
      s[4] += p1.x; s[5] += p1.y; s[6] += p1.z; s[7] += p1.w;
      // owner wave factors the 8x8 diagonal block with shuffles (rows j0..j0+7)
      if ((i >> 3) == (j0 >> 3)) {
        const int base = j0 & 63;
        const int r = i & 7;  // row within panel (j0 multiple of 8)
        float l[8], di[8];
#pragma unroll
        for (int m = 0; m < 8; ++m) {
          const float smv = __shfl(s[m], base + m);
          const float d = sqrtf(smv);
          const float dinv = 1.0f / d;
          di[m] = dinv;
          float lm;
          if (r == m) lm = d;
          else if (r > m) lm = s[m] * dinv;
          else lm = 0.0f;
          l[m] = lm;
#pragma unroll
          for (int mm = m + 1; mm < 8; ++mm) {
            s[mm] = fmaf(-lm, __shfl(lm, base + mm), s[mm]);
          }
        }
#pragma unroll
        for (int m = 0; m < 8; ++m) pnl[r * 8 + m] = (m < r) ? l[m] : ((m == r) ? di[r] : 0.0f);
#pragma unroll
        for (int m = 0; m < 8; ++m) L[(size_t)(j0 + m) * N_ + i] = l[m];
      }
    }
    __syncthreads();  // C: pnl ready

    if (half == 0 && (i >> 3) != (j0 >> 3)) {
      float l[8];
      if (i > j0) {  // i >= j0+8: trailing rows
#pragma unroll
        for (int m = 0; m < 8; ++m) {
          float sm = s[m];
#pragma unroll
          for (int mm = 0; mm < 8; ++mm) {
            if (mm < m) sm = fmaf(-l[mm], pnl[m * 8 + mm], sm);
          }
          l[m] = sm * pnl[m * 8 + m];
        }
      } else {
#pragma unroll
        for (int m = 0; m < 8; ++m) l[m] = 0.0f;  // zeros above diag keep history branch-free
      }
#pragma unroll
      for (int m = 0; m < 8; ++m) L[(size_t)(j0 + m) * N_ + i] = l[m];
    }
    __syncthreads();  // D: L writes visible before next slab fill
  }
}

// ---------------- pack L: Lc fp32 -> Lc16 (bf16) + Lr16 (bf16 transposed) ----------------
__global__ __launch_bounds__(256) void lpack_kernel(const float* __restrict__ Lc,
                                                    uint16_t* __restrict__ Lc16,
                                                    uint16_t* __restrict__ Lr16) {
  const int b = blockIdx.x;
  const float* Lp = Lc + (size_t)b * N_ * N_;
  uint16_t* C16 = Lc16 + (size_t)b * N_ * N_;
  uint16_t* R16 = Lr16 + (size_t)b * N_ * N_;
  __shared__ float tl[32][33];
  const int tx = threadIdx.x & 31;
  const int ty = threadIdx.x >> 5;
  for (int kt = 0; kt < 8; ++kt) {
    for (int it = 0; it < 8; ++it) {
#pragma unroll
      for (int rr = 0; rr < 4; ++rr) {
        const int k = kt * 32 + ty + 8 * rr;
        const int ii = it * 32 + tx;
        const float v = Lp[(size_t)k * N_ + ii];
        tl[ty + 8 * rr][tx] = v;
        C16[(size_t)k * N_ + ii] = f2b(v);
      }
      __syncthreads();
#pragma unroll
      for (int rr = 0; rr < 4; ++rr) {
        const int ii = it * 32 + ty + 8 * rr;
        const int k = kt * 32 + tx;
        R16[(size_t)ii * N_ + k] = f2b(tl[tx][ty + 8 * rr]);
      }
      __syncthreads();
    }
  }
}

// ---------------- eps fp32 -> epsT16 + epsrm16 (bf16); zero bar ----------------
__global__ __launch_bounds__(256) void etrans_kernel(const float* __restrict__ eps,
                                                     uint16_t* __restrict__ epsT16,
                                                     uint16_t* __restrict__ epsrm16,
                                                     int* __restrict__ bar) {
  const int b = blockIdx.x;
  const int s0 = blockIdx.y * 50;
  const int t = threadIdx.x;
  if (blockIdx.x == 0 && blockIdx.y == 0 && t < 64) bar[t] = 0;
  __shared__ float tl[50][257];
  const float* E = eps + ((size_t)b * S_ + s0) * N_;
  for (int p = 0; p < 50; ++p) tl[p][t] = E[(size_t)p * N_ + t];
  __syncthreads();
  uint16_t* RM = epsrm16 + ((size_t)b * S_ + s0) * N_;
  for (int p = 0; p < 50; ++p) RM[(size_t)p * N_ + t] = f2b(tl[p][t]);
  uint16_t* ET = epsT16 + (size_t)b * N_ * S_;
  const int g = t / 50, ss = t % 50;
  if (g < 5) {
    for (int q = 0; q < 52; ++q) {
      const int n = q * 5 + g;
      if (n < N_) ET[(size_t)n * S_ + s0 + ss] = f2b(tl[ss][n]);
    }
  }
}

// ---------------- cooperative solver: 4 blocks (1024 thr) per batch ----------------
__global__ __launch_bounds__(1024) void solve_kernel(
    const float* __restrict__ mu, const int* __restrict__ pcrisis,
    const int* __restrict__ plam, const uint16_t* __restrict__ Lc16,
    const uint16_t* __restrict__ Lr16, const uint16_t* __restrict__ epsT16,
    const uint16_t* __restrict__ epsrm16, unsigned* __restrict__ lossbits,
    int* __restrict__ bar, float* __restrict__ out) {
  const int bx = blockIdx.x;
  const int b = bx & (B_ - 1);
  const int part = bx >> 6;  // {b, b+64, b+128, b+192} land on the same XCD under %8 RR
  const int t = threadIdx.x;
  const int ln = t & 63;
  const int wv = t >> 6;
  const int s0 = part * SCH_;

  __shared__ __align__(16) float w_s[N_];
  __shared__ __align__(16) float v_s[N_];
  __shared__ __align__(16) float e_s[N_];
  __shared__ __align__(16) float u_s[N_];
  __shared__ __align__(16) float ph[PART_][SCH_];
  __shared__ __align__(16) float scratch[8][N_];
  __shared__ __align__(16) float loss_s[S_];
  __shared__ int lists[S_];
  __shared__ int whist[2][16][256];  // ping-pong per-wave histograms
  __shared__ float c_sh;
  __shared__ unsigned pref_sh;
  __shared__ int r_sh;
  __shared__ int lcnt;
  __shared__ float sum_sh;

  const int crisis = pcrisis[0];
  const int lamv = plam[0];
  const float muf = 1.0f + ((lamv > 0) ? (1.0f / fmaxf((float)lamv, 0.1f)) : 0.0f);
  const float fl_bil = SAFETY_ * (float)crisis;
  const float mass = 1.0f - fl_bil;

  const uint16_t* LcB = Lc16 + (size_t)b * N_ * N_;
  const uint16_t* LrB = Lr16 + (size_t)b * N_ * N_;
  const float* muB = mu + (size_t)b * N_;
  const uint16_t* epsTB = epsT16 + (size_t)b * N_ * S_;
  const uint16_t* epsRB = epsrm16 + (size_t)b * S_ * N_;

  // init: zero both histogram banks; w0 = proj(uniform)
  for (int x = t; x < 2 * 16 * 256; x += 1024) ((int*)whist)[x] = 0;
  if (t < 64) {
    float y[4];
#pragma unroll
    for (int j = 0; j < 4; ++j) y[j] = 1.0f / (float)N_;
    proj_store(y, fl_bil, mass, muf, muB, ln, w_s, &c_sh);
  }
  __syncthreads();

  for (int it = 0; it < NITER_; ++it) {
    // ---- v = L^T w : v_k = sum_i Lr[i*N+k] * w[i] ----
    {
      const int oct = t >> 7, kp = t & 127;
      const uint32_t* Lp = (const uint32_t*)(LrB) + kp;
      const int i0 = 32 * oct;
      float a0 = 0.0f, a1 = 0.0f;
#pragma unroll 8
      for (int ii = 0; ii < 32; ++ii) {
        const uint32_t u = Lp[(size_t)(i0 + ii) * (N_ / 2)];
        const float ww = w_s[i0 + ii];
        a0 = fmaf(blo(u), ww, a0);
        a1 = fmaf(bhi(u), ww, a1);
      }
      *(float2*)&scratch[oct][2 * kp] = make_float2(a0, a1);
    }
    __syncthreads();
    if (t < N_) {
      v_s[t] = ((scratch[0][t] + scratch[1][t]) + (scratch[2][t] + scratch[3][t])) +
               ((scratch[4][t] + scratch[5][t]) + (scratch[6][t] + scratch[7][t]));
    }
    __syncthreads();

    // ---- stage 1: partial losses for my 500 scenarios ----
    const float cc = c_sh;
    {
      const int q = t >> 8;     // n-quarter
      const int idx = t & 255;  // scenario-pair
      if (idx < SCH_ / 2) {
        const uint32_t* col = (const uint32_t*)(epsTB + (size_t)(64 * q) * S_ + (s0 + 2 * idx));
        float a0 = 0.0f, a1 = 0.0f;
#pragma unroll 8
        for (int j = 0; j < 64; ++j) {
          const uint32_t u = col[(size_t)j * (S_ / 2)];
          const float vv = v_s[64 * q + j];
          a0 = fmaf(blo(u), vv, a0);
          a1 = fmaf(bhi(u), vv, a1);
        }
        *(float2*)&ph[q][2 * idx] = make_float2(a0, a1);
      }
    }
    __syncthreads();
    // combine + publish (relaxed agent atomics: per-access coherent, NO cache-wide fences)
    unsigned* lgbuf = lossbits + ((it & 1) ? (size_t)B_ * S_ : 0) + (size_t)b * S_;
    if (t < SCH_) {
      const float lv = -(cc + ((ph[0][t] + ph[1][t]) + (ph[2][t] + ph[3][t])));
      loss_s[s0 + t] = lv;
      __hip_atomic_store(&lgbuf[s0 + t], __float_as_uint(lv), __ATOMIC_RELAXED,
                         __HIP_MEMORY_SCOPE_AGENT);
    }
    __syncthreads();  // drains vmcnt for all waves before barrier exit
    if (t == 0) {
      __hip_atomic_fetch_add(&bar[b], 1, __ATOMIC_RELAXED, __HIP_MEMORY_SCOPE_AGENT);
      const int target = PART_ * (it + 1);
      while (__hip_atomic_load(&bar[b], __ATOMIC_RELAXED, __HIP_MEMORY_SCOPE_AGENT) < target) {
        __builtin_amdgcn_s_sleep(2);
      }
    }
    __syncthreads();
    // gather the other parts' losses
    for (int s = t; s < S_; s += 1024) {
      if ((unsigned)(s - s0) >= (unsigned)SCH_) {
        loss_s[s] = __uint_as_float(
            __hip_atomic_load(&lgbuf[s], __ATOMIC_RELAXED, __HIP_MEMORY_SCOPE_AGENT));
      }
    }
    __syncthreads();

    // ---- top-K threshold: 4-pass radix select, per-wave histograms ----
    unsigned pref = 0;
    int r = K_;
    for (int pass = 0; pass < 4; ++pass) {
      const int shift = 24 - 8 * pass;
      int(*H)[256] = whist[pass & 1];
      const unsigned msk = (pass == 0) ? 0u : (0xFFFFFFFFu << (shift + 8));
      {
        const unsigned k0 = keyd(loss_s[t]);
        if ((k0 & msk) == pref) atomicAdd(&H[wv][(k0 >> shift) & 255], 1);
        if (t + 1024 < S_) {
          const unsigned k1 = keyd(loss_s[t + 1024]);
          if ((k1 & msk) == pref) atomicAdd(&H[wv][(k1 >> shift) & 255], 1);
        }
      }
      __syncthreads();
      if (t < 64) {  // wave 0: reduce 16 hists + rank scan + digit pick
        const int base = 4 * ln;
        int c0 = 0, c1 = 0, c2 = 0, c3 = 0;
#pragma unroll
        for (int w = 0; w < 16; ++w) {
          c0 += H[w][base];
          c1 += H[w][base + 1];
          c2 += H[w][base + 2];
          c3 += H[w][base + 3];
        }
        const int tot = c0 + c1 + c2 + c3;
        int sc = tot;
#pragma unroll
        for (int off = 1; off < 64; off <<= 1) {
          const int o = __shfl_up(sc, off);
          if (ln >= off) sc += o;
        }
        const int excl = sc - tot;
        const bool has = (excl < r) && (r <= sc);
        const unsigned long long bal = __ballot(has);
        const int lstar = __ffsll(bal) - 1;
        if (ln == lstar) {
          const int rr = r - excl;
          int d, rn;
          if (rr <= c0) { d = 0; rn = rr; }
          else if (rr <= c0 + c1) { d = 1; rn = rr - c0; }
          else if (rr <= c0 + c1 + c2) { d = 2; rn = rr - c0 - c1; }
          else { d = 3; rn = rr - c0 - c1 - c2; }
          pref_sh = pref | ((unsigned)(base + d) << shift);
          r_sh = rn;
        }
      } else {
        // waves 1..15: zero the other bank for the next pass / next iteration
        for (int x = t - 64; x < 16 * 256; x += 960) ((int*)whist[(pass + 1) & 1])[x] = 0;
        if (pass == 3 && t == 64) lcnt = 0;
      }
      __syncthreads();
      pref = pref_sh;
      r = r_sh;
    }
    float thresh;
    {
      const unsigned kd = pref;
      const unsigned ub = (kd & 0x80000000u) ? kd : ((~kd) & 0x7FFFFFFFu);
      thresh = __uint_as_float(ub);
    }

    // ---- compact selected scenarios ----
    for (int s = t; s < S_; s += 1024) {
      if (loss_s[s] >= thresh) {
        const int p = atomicAdd(&lcnt, 1);
        lists[p] = s;
      }
    }
    __syncthreads();
    const int cnt = lcnt;
    const float weight = 1.0f / (float)((cnt > K_) ? cnt : K_);

    // ---- e = sum of selected eps rows: 8 row-groups x 128 n-pairs into scratch ----
    {
      const int rt = t >> 7;   // row-group
      const int np = t & 127;  // n-pair
      float a0 = 0.0f, a1 = 0.0f;
      for (int p = rt; p < cnt; p += 8) {
        const uint32_t u = *((const uint32_t*)(epsRB + (size_t)lists[p] * N_) + np);
        a0 += blo(u);
        a1 += bhi(u);
      }
      *(float2*)&scratch[rt][2 * np] = make_float2(a0, a1);
    }
    __syncthreads();
    if (t < N_) {
      e_s[t] = ((scratch[0][t] + scratch[1][t]) + (scratch[2][t] + scratch[3][t])) +
               ((scratch[4][t] + scratch[5][t]) + (scratch[6][t] + scratch[7][t]));
    }
    __syncthreads();

    // ---- u = L e : u_i = sum_k Lc[k*N+i] e[k] ----
    {
      const int oct = t >> 7, ip = t & 127;
      const uint32_t* Lp = (const uint32_t*)(LcB) + ip;
      const int k0 = 32 * oct;
      float a0 = 0.0f, a1 = 0.0f;
#pragma unroll 8
      for (int kk = 0; kk < 32; ++kk) {
        const uint32_t u = Lp[(size_t)(k0 + kk) * (N_ / 2)];
        const float ee = e_s[k0 + kk];
        a0 = fmaf(blo(u), ee, a0);
        a1 = fmaf(bhi(u), ee, a1);
      }
      *(float2*)&scratch[oct][2 * ip] = make_float2(a0, a1);
    }
    __syncthreads();
    if (t < N_) {
      u_s[t] = (((scratch[0][t] + scratch[1][t]) + (scratch[2][t] + scratch[3][t])) +
                ((scratch[4][t] + scratch[5][t]) + (scratch[6][t] + scratch[7][t]))) * weight;
    }
    __syncthreads();

    // ---- w <- proj(w + lr*(mu_eff + u)) ----
    if (t < 64) {
      const float lr = 0.5f / sqrtf((float)it + 1.0f);
      const float4 w4 = *(const float4*)(w_s + 4 * ln);
      const float4 u4 = *(const float4*)(u_s + 4 * ln);
      const float4 m4 = *(const float4*)(muB + 4 * ln);
      float y[4];
      y[0] = w4.x + lr * (muf * m4.x + u4.x);
      y[1] = w4.y + lr * (muf * m4.y + u4.y);
      y[2] = w4.z + lr * (muf * m4.z + u4.z);
      y[3] = w4.w + lr * (muf * m4.w + u4.w);
      proj_store(y, fl_bil, mass, muf, muB, ln, w_s, &c_sh);
    }
    __syncthreads();
  }

  // ---- output (part 0 only): w / (sum + 1e-8) ----
  if (part == 0) {
    if (t < 64) {
      const float4 w4 = *(const float4*)(w_s + 4 * ln);
      const float ssum = wred_f(w4.x + w4.y + w4.z + w4.w);
      if (ln == 0) sum_sh = ssum;
    }
    __syncthreads();
    if (t < N_) out[(size_t)b * N_ + t] = fmaxf(w_s[t], 0.0f) / (sum_sh + 1e-8f);
  }
}

extern "C" void kernel_launch(void* const* d_in, const int* in_sizes, int n_in,
                              void* d_out, int out_size, void* d_ws, size_t ws_size,
                              hipStream_t stream) {
  const float* mu = (const float*)d_in[0];
  const float* sigma = (const float*)d_in[1];
  const float* eps = (const float*)d_in[2];
  const int* crisis = (const int*)d_in[3];
  const int* lam = (const int*)d_in[4];
  float* out = (float*)d_out;
  float* ws = (float*)d_ws;

  uint16_t* Lc16 = (uint16_t*)(ws + OFF_LC16);
  uint16_t* Lr16 = (uint16_t*)(ws + OFF_LR16);
  uint16_t* epsT16 = (uint16_t*)(ws + OFF_EPST);
  uint16_t* epsrm16 = (uint16_t*)(ws + OFF_EPSRM);
  float* Lc = ws + OFF_EPSRM;  // fp32 L aliases epsrm16 (dead before etrans writes it)
  unsigned* lossbits = (unsigned*)(ws + OFF_LOSS);
  int* bar = (int*)(ws + OFF_BAR);

  chol_kernel<<<dim3(B_), dim3(512), 0, stream>>>(sigma, Lc);
  lpack_kernel<<<dim3(B_), dim3(256), 0, stream>>>(Lc, Lc16, Lr16);
  etrans_kernel<<<dim3(B_, S_ / 50), dim3(256), 0, stream>>>(eps, epsT16, epsrm16, bar);

  void* args[] = {(void*)&mu,    (void*)&crisis, (void*)&lam,     (void*)&Lc16,
                  (void*)&Lr16,  (void*)&epsT16, (void*)&epsrm16, (void*)&lossbits,
                  (void*)&bar,   (void*)&out};
  hipLaunchCooperativeKernel((void*)solve_kernel, dim3(PART_ * B_), dim3(1024), args, 0, stream);
}